// Round 2
// baseline (246.417 us; speedup 1.0000x reference)
//
#include <hip/hip_runtime.h>

typedef __bf16 bf16_t;
typedef __attribute__((ext_vector_type(8))) __bf16 bf16x8;
typedef __attribute__((ext_vector_type(4))) float f32x4;

#define QF   64
#define GG   120
#define HID  128
#define NACT 20
#define BTOT 2048   // B*T

// ---- workspace layout (bytes) ----
#define WEFFH_OFF 0u          // 120*128*64 bf16 (transposed [u][h][r]) = 1,966,080
#define WEFFL_OFF 1966080u    // 1,966,080
#define XH_OFF    3932160u    // 2048*64 bf16 = 262,144
#define XL_OFF    4194304u    // 262,144
#define W1TH_OFF  4456448u    // 128*128 bf16 (transposed [n][k]) = 32,768
#define W1TL_OFF  4489216u    // 32,768
#define M_OFF     4521984u    // 120*2048 f32 = 983,040
#define MISC_OFF  5505024u    // bmean[128], wmean[128], cb -> 1088 reserved
#define GMAP_OFF  5506112u    // 120*120 i32 = 57,600
#define FPINV_OFF 5563712u    // 120*64 i32  = 30,720
#define UBYC_OFF  5594432u    // 20*6 i32    = 480

__device__ __forceinline__ unsigned short f2bf(float f) {
    unsigned int u = __float_as_uint(f);
    unsigned int r = u + 0x7fffu + ((u >> 16) & 1u);
    return (unsigned short)(r >> 16);
}
__device__ __forceinline__ float bf2f(unsigned short h) {
    return __uint_as_float(((unsigned int)h) << 16);
}

__device__ __forceinline__ void idx_to_perm(int i, int p[5]) {
    int avail[5] = {0, 1, 2, 3, 4};
    const int f[4] = {24, 6, 2, 1};
    for (int k = 0; k < 4; ++k) {
        int d = i / f[k]; i %= f[k];
        p[k] = avail[d];
        for (int j = d; j < 4 - k; ++j) avail[j] = avail[j + 1];
    }
    p[4] = avail[0];
}

__device__ __forceinline__ int perm_to_idx(const int p[5]) {
    const int f[4] = {24, 6, 2, 1};
    int idx = 0;
    for (int k = 0; k < 4; ++k) {
        int c = 0;
        for (int j = k + 1; j < 5; ++j) c += (p[j] < p[k]) ? 1 : 0;
        idx += c * f[k];
    }
    return idx;
}

__global__ void build_tables(int* __restrict__ gmap, int* __restrict__ fpinv,
                             int* __restrict__ ubycoset) {
    __shared__ int perms[GG][5];
    __shared__ int invp[GG];
    int t = threadIdx.x;
    if (t < GG) {
        int p[5]; idx_to_perm(t, p);
        for (int k = 0; k < 5; ++k) perms[t][k] = p[k];
        int q[5];
        for (int k = 0; k < 5; ++k) q[p[k]] = k;
        invp[t] = perm_to_idx(q);
    }
    __syncthreads();
    if (t < GG) {
        for (int r = 0; r < QF; ++r) {
            int v = r & 32;
            for (int k = 0; k < 5; ++k) {
                int bit = (r >> (4 - perms[t][k])) & 1;
                v |= bit << (4 - k);
            }
            fpinv[t * QF + r] = v;
        }
        for (int p = 0; p < GG; ++p) {
            int j = invp[p];
            int comp[5];
            for (int mM = 0; mM < 5; ++mM) comp[mM] = perms[t][perms[j][mM]];
            int h = perm_to_idx(comp);
            gmap[t * GG + h] = p;
        }
    }
    __syncthreads();
    if (t == 0) {
        int cnt[NACT];
        for (int a = 0; a < NACT; ++a) cnt[a] = 0;
        for (int p = 0; p < GG; ++p) {
            int a0 = perms[p][0], a1 = perms[p][1];
            int a = a0 * 4 + (a1 > a0 ? a1 - 1 : a1);
            ubycoset[a * 6 + cnt[a]++] = p;
        }
    }
}

__global__ void build_misc(const float* __restrict__ eq_bias,
                           const float* __restrict__ Wout,
                           const float* __restrict__ bout,
                           float* __restrict__ misc) {
    int h = threadIdx.x;   // 128
    float s = 0.f;
    for (int g = 0; g < GG; ++g) s += eq_bias[g * HID + h];
    misc[h] = s * (1.f / GG);
    float w = 0.f;
    for (int n = 0; n < NACT; ++n) w += Wout[h * NACT + n];
    misc[HID + h] = w * (1.f / NACT);
    if (h == 0) {
        float c = 0.f;
        for (int n = 0; n < NACT; ++n) c += bout[n];
        misc[2 * HID] = c * (1.f / NACT);
    }
}

__global__ void split_x(const float* __restrict__ x,
                        unsigned short* __restrict__ xh,
                        unsigned short* __restrict__ xl) {
    int i = blockIdx.x * 256 + threadIdx.x;
    if (i >= BTOT * QF) return;
    float f = x[i];
    unsigned short h = f2bf(f);
    xh[i] = h;
    xl[i] = f2bf(f - bf2f(h));
}

__global__ void split_w1t(const float* __restrict__ W1,
                          unsigned short* __restrict__ w1th,
                          unsigned short* __restrict__ w1tl) {
    int i = blockIdx.x * 256 + threadIdx.x;   // 128*128
    if (i >= HID * HID) return;
    int k = i >> 7, n = i & 127;
    float f = W1[k * HID + n];
    unsigned short h = f2bf(f);
    w1th[n * HID + k] = h;
    w1tl[n * HID + k] = f2bf(f - bf2f(h));
}

// Weff_t[u][h][r] = (1/120) sum_p eqw[gmap[u][p]][fpinv[p][r]][h], split hi/lo bf16
__global__ void build_weff_t(const float* __restrict__ eqw,
                             const int* __restrict__ gmap,
                             const int* __restrict__ fpinv,
                             unsigned short* __restrict__ weffh,
                             unsigned short* __restrict__ weffl) {
    int h = threadIdx.x;                 // 128
    int blk = blockIdx.x;                // u*64 + r
    int u = blk >> 6, r = blk & 63;
    float acc = 0.f;
    for (int p = 0; p < GG; ++p) {
        int g = gmap[u * GG + p];
        int q = fpinv[p * QF + r];
        acc += eqw[(g * QF + q) * HID + h];
    }
    acc *= (1.f / GG);
    unsigned short hh = f2bf(acc);
    weffh[(u * HID + h) * QF + r] = hh;
    weffl[(u * HID + h) * QF + r] = f2bf(acc - bf2f(hh));
}

#define LSTR 136   // LDS row stride in bf16 elems (272 B, 16B-aligned rows)

__global__ __launch_bounds__(256)
void mlp_mfma(const unsigned short* __restrict__ xh,
              const unsigned short* __restrict__ xl,
              const unsigned short* __restrict__ weffh,
              const unsigned short* __restrict__ weffl,
              const unsigned short* __restrict__ w1th,
              const unsigned short* __restrict__ w1tl,
              const float* __restrict__ b1,
              const float* __restrict__ misc,
              float* __restrict__ m) {
    __shared__ unsigned short hbuf[2][4][16 * LSTR];
    int u = blockIdx.y;
    int tid = threadIdx.x;
    int w = tid >> 6, lane = tid & 63;
    int lm = lane & 15, kg = lane >> 4;
    int rowbase = blockIdx.x * 64 + w * 16;

    // ---- stage A: E(16x128 per wave) = X(16x64) @ Weff_t[u]^T ----
    f32x4 acc[8];
#pragma unroll
    for (int t = 0; t < 8; ++t) acc[t] = (f32x4){0.f, 0.f, 0.f, 0.f};

    const unsigned short* xhp = xh + (rowbase + lm) * QF + kg * 8;
    const unsigned short* xlp = xl + (rowbase + lm) * QF + kg * 8;
    const unsigned short* wh = weffh + (unsigned)(u * HID) * QF;
    const unsigned short* wl = weffl + (unsigned)(u * HID) * QF;
#pragma unroll
    for (int ks = 0; ks < 2; ++ks) {
        bf16x8 ah = *(const bf16x8*)(xhp + ks * 32);
        bf16x8 al = *(const bf16x8*)(xlp + ks * 32);
#pragma unroll
        for (int nt = 0; nt < 8; ++nt) {
            const unsigned short* bp = wh + (nt * 16 + lm) * QF + ks * 32 + kg * 8;
            const unsigned short* bq = wl + (nt * 16 + lm) * QF + ks * 32 + kg * 8;
            bf16x8 bh = *(const bf16x8*)bp;
            bf16x8 bl = *(const bf16x8*)bq;
            acc[nt] = __builtin_amdgcn_mfma_f32_16x16x32_bf16(ah, bh, acc[nt], 0, 0, 0);
            acc[nt] = __builtin_amdgcn_mfma_f32_16x16x32_bf16(ah, bl, acc[nt], 0, 0, 0);
            acc[nt] = __builtin_amdgcn_mfma_f32_16x16x32_bf16(al, bh, acc[nt], 0, 0, 0);
        }
    }

    // ---- relu(e + bmean), split hi/lo -> per-wave LDS tile (transpose) ----
    unsigned short* Hh = &hbuf[0][w][0];
    unsigned short* Hl = &hbuf[1][w][0];
#pragma unroll
    for (int nt = 0; nt < 8; ++nt) {
        int col = nt * 16 + lm;
        float bm = misc[col];
#pragma unroll
        for (int r = 0; r < 4; ++r) {
            int row = kg * 4 + r;
            float e = acc[nt][r] + bm;
            e = e > 0.f ? e : 0.f;
            unsigned short eh = f2bf(e);
            unsigned short el = f2bf(e - bf2f(eh));
            Hh[row * LSTR + col] = eh;
            Hl[row * LSTR + col] = el;
        }
    }
    // same-wave LDS write->read: compiler inserts lgkmcnt wait; no __syncthreads needed

    // ---- stage B: H2(16x128) = H(16x128) @ W1t^T ----
    f32x4 acc2[8];
#pragma unroll
    for (int t = 0; t < 8; ++t) acc2[t] = (f32x4){0.f, 0.f, 0.f, 0.f};
#pragma unroll
    for (int ks = 0; ks < 4; ++ks) {
        bf16x8 ah = *(const bf16x8*)(Hh + lm * LSTR + ks * 32 + kg * 8);
        bf16x8 al = *(const bf16x8*)(Hl + lm * LSTR + ks * 32 + kg * 8);
#pragma unroll
        for (int nt = 0; nt < 8; ++nt) {
            bf16x8 bh = *(const bf16x8*)(w1th + (nt * 16 + lm) * HID + ks * 32 + kg * 8);
            bf16x8 bl = *(const bf16x8*)(w1tl + (nt * 16 + lm) * HID + ks * 32 + kg * 8);
            acc2[nt] = __builtin_amdgcn_mfma_f32_16x16x32_bf16(ah, bh, acc2[nt], 0, 0, 0);
            acc2[nt] = __builtin_amdgcn_mfma_f32_16x16x32_bf16(ah, bl, acc2[nt], 0, 0, 0);
            acc2[nt] = __builtin_amdgcn_mfma_f32_16x16x32_bf16(al, bh, acc2[nt], 0, 0, 0);
        }
    }

    // ---- epilogue: m = relu(h2 + b1) . wmean, reduce over 16 lanes ----
    float ms[4] = {0.f, 0.f, 0.f, 0.f};
#pragma unroll
    for (int nt = 0; nt < 8; ++nt) {
        int col = nt * 16 + lm;
        float bb = b1[col];
        float wm = misc[HID + col];
#pragma unroll
        for (int r = 0; r < 4; ++r) {
            float v = acc2[nt][r] + bb;
            v = v > 0.f ? v : 0.f;
            ms[r] += v * wm;
        }
    }
#pragma unroll
    for (int off = 1; off < 16; off <<= 1) {
#pragma unroll
        for (int r = 0; r < 4; ++r) ms[r] += __shfl_xor(ms[r], off);
    }
    if (lm == 0) {
#pragma unroll
        for (int r = 0; r < 4; ++r)
            m[u * BTOT + rowbase + kg * 4 + r] = ms[r];
    }
}

__global__ void reduce_out(const float* __restrict__ m,
                           const int* __restrict__ ubycoset,
                           const float* __restrict__ misc,
                           float* __restrict__ out) {
    int idx = blockIdx.x * 256 + threadIdx.x;   // bt*20 + a
    if (idx >= BTOT * NACT) return;
    int bt = idx / NACT, a = idx % NACT;
    float s = 0.f;
#pragma unroll
    for (int j = 0; j < 6; ++j) s += m[ubycoset[a * 6 + j] * BTOT + bt];
    out[idx] = s * (1.f / 6.f) + misc[2 * HID];
}

extern "C" void kernel_launch(void* const* d_in, const int* in_sizes, int n_in,
                              void* d_out, int out_size, void* d_ws, size_t ws_size,
                              hipStream_t stream) {
    const float* x       = (const float*)d_in[0];
    const float* eqw     = (const float*)d_in[1];
    const float* eq_bias = (const float*)d_in[2];
    const float* W1      = (const float*)d_in[3];
    const float* b1      = (const float*)d_in[4];
    const float* Wout    = (const float*)d_in[5];
    const float* bout    = (const float*)d_in[6];
    float* out           = (float*)d_out;

    char* ws = (char*)d_ws;
    unsigned short* weffh = (unsigned short*)(ws + WEFFH_OFF);
    unsigned short* weffl = (unsigned short*)(ws + WEFFL_OFF);
    unsigned short* xhb   = (unsigned short*)(ws + XH_OFF);
    unsigned short* xlb   = (unsigned short*)(ws + XL_OFF);
    unsigned short* w1th  = (unsigned short*)(ws + W1TH_OFF);
    unsigned short* w1tl  = (unsigned short*)(ws + W1TL_OFF);
    float* mbuf   = (float*)(ws + M_OFF);
    float* misc   = (float*)(ws + MISC_OFF);
    int* gmap     = (int*)(ws + GMAP_OFF);
    int* fpinv    = (int*)(ws + FPINV_OFF);
    int* ubycoset = (int*)(ws + UBYC_OFF);

    hipLaunchKernelGGL(build_tables, dim3(1), dim3(128), 0, stream,
                       gmap, fpinv, ubycoset);
    hipLaunchKernelGGL(build_misc, dim3(1), dim3(128), 0, stream,
                       eq_bias, Wout, bout, misc);
    hipLaunchKernelGGL(split_x, dim3((BTOT * QF + 255) / 256), dim3(256), 0, stream,
                       x, xhb, xlb);
    hipLaunchKernelGGL(split_w1t, dim3((HID * HID + 255) / 256), dim3(256), 0, stream,
                       W1, w1th, w1tl);
    hipLaunchKernelGGL(build_weff_t, dim3(GG * QF), dim3(HID), 0, stream,
                       eqw, gmap, fpinv, weffh, weffl);
    hipLaunchKernelGGL(mlp_mfma, dim3(32, GG), dim3(256), 0, stream,
                       xhb, xlb, weffh, weffl, w1th, w1tl, b1, misc, mbuf);
    hipLaunchKernelGGL(reduce_out, dim3((BTOT * NACT + 255) / 256), dim3(256), 0, stream,
                       mbuf, ubycoset, misc, out);
}

// Round 3
// 132.521 us; speedup vs baseline: 1.8595x; 1.8595x over previous
//
#include <hip/hip_runtime.h>

typedef __bf16 bf16_t;
typedef __attribute__((ext_vector_type(8))) __bf16 bf16x8;
typedef __attribute__((ext_vector_type(4))) float f32x4;
typedef __attribute__((ext_vector_type(8))) unsigned short ushort8;

#define QF   64
#define GG   120
#define HID  128
#define NACT 20
#define BTOT 2048   // B*T

// ---- workspace layout (bytes) ----
#define WEFFH_OFF 0u          // 120*128*64 bf16 (transposed [u][h][r]) = 1,966,080
#define WEFFL_OFF 1966080u
#define XH_OFF    3932160u    // 2048*64 bf16 = 262,144
#define XL_OFF    4194304u
#define W1TH_OFF  4456448u    // 128*128 bf16 (transposed [n][k]) = 32,768
#define W1TL_OFF  4489216u
#define M_OFF     4521984u    // 120*2048 f32 = 983,040
#define MISC_OFF  5505024u    // bmean[128], wmean[128], cb
#define GMAP_OFF  5506112u    // 120*120 i32
#define FPINV_OFF 5563712u    // 120*64 i32
#define UBYC_OFF  5594432u    // 20*6 i32

__device__ __forceinline__ unsigned short f2bf(float f) {
    unsigned int u = __float_as_uint(f);
    unsigned int r = u + 0x7fffu + ((u >> 16) & 1u);
    return (unsigned short)(r >> 16);
}
__device__ __forceinline__ float bf2f(unsigned short h) {
    return __uint_as_float(((unsigned int)h) << 16);
}

__device__ __forceinline__ void idx_to_perm(int i, int p[5]) {
    int avail[5] = {0, 1, 2, 3, 4};
    const int f[4] = {24, 6, 2, 1};
    for (int k = 0; k < 4; ++k) {
        int d = i / f[k]; i %= f[k];
        p[k] = avail[d];
        for (int j = d; j < 4 - k; ++j) avail[j] = avail[j + 1];
    }
    p[4] = avail[0];
}

__device__ __forceinline__ int perm_to_idx(const int p[5]) {
    const int f[4] = {24, 6, 2, 1};
    int idx = 0;
    for (int k = 0; k < 4; ++k) {
        int c = 0;
        for (int j = k + 1; j < 5; ++j) c += (p[j] < p[k]) ? 1 : 0;
        idx += c * f[k];
    }
    return idx;
}

__global__ void build_tables(int* __restrict__ gmap, int* __restrict__ fpinv,
                             int* __restrict__ ubycoset) {
    __shared__ int perms[GG][5];
    __shared__ int invp[GG];
    int t = threadIdx.x;
    if (t < GG) {
        int p[5]; idx_to_perm(t, p);
        for (int k = 0; k < 5; ++k) perms[t][k] = p[k];
        int q[5];
        for (int k = 0; k < 5; ++k) q[p[k]] = k;
        invp[t] = perm_to_idx(q);
    }
    __syncthreads();
    if (t < GG) {
        for (int r = 0; r < QF; ++r) {
            int v = r & 32;
            for (int k = 0; k < 5; ++k) {
                int bit = (r >> (4 - perms[t][k])) & 1;
                v |= bit << (4 - k);
            }
            fpinv[t * QF + r] = v;
        }
        for (int p = 0; p < GG; ++p) {
            int j = invp[p];
            int comp[5];
            for (int mM = 0; mM < 5; ++mM) comp[mM] = perms[t][perms[j][mM]];
            int h = perm_to_idx(comp);
            gmap[t * GG + h] = p;
        }
    }
    __syncthreads();
    if (t == 0) {
        int cnt[NACT];
        for (int a = 0; a < NACT; ++a) cnt[a] = 0;
        for (int p = 0; p < GG; ++p) {
            int a0 = perms[p][0], a1 = perms[p][1];
            int a = a0 * 4 + (a1 > a0 ? a1 - 1 : a1);
            ubycoset[a * 6 + cnt[a]++] = p;
        }
    }
}

__global__ void build_misc(const float* __restrict__ eq_bias,
                           const float* __restrict__ Wout,
                           const float* __restrict__ bout,
                           float* __restrict__ misc) {
    int h = threadIdx.x;   // 128
    float s = 0.f;
    for (int g = 0; g < GG; ++g) s += eq_bias[g * HID + h];
    misc[h] = s * (1.f / GG);
    float w = 0.f;
    for (int n = 0; n < NACT; ++n) w += Wout[h * NACT + n];
    misc[HID + h] = w * (1.f / NACT);
    if (h == 0) {
        float c = 0.f;
        for (int n = 0; n < NACT; ++n) c += bout[n];
        misc[2 * HID] = c * (1.f / NACT);
    }
}

__global__ void split_x(const float* __restrict__ x,
                        unsigned short* __restrict__ xh,
                        unsigned short* __restrict__ xl) {
    int i = blockIdx.x * 256 + threadIdx.x;
    if (i >= BTOT * QF) return;
    float f = x[i];
    unsigned short h = f2bf(f);
    xh[i] = h;
    xl[i] = f2bf(f - bf2f(h));
}

__global__ void split_w1t(const float* __restrict__ W1,
                          unsigned short* __restrict__ w1th,
                          unsigned short* __restrict__ w1tl) {
    int i = blockIdx.x * 256 + threadIdx.x;   // 128*128
    if (i >= HID * HID) return;
    int k = i >> 7, n = i & 127;
    float f = W1[k * HID + n];
    unsigned short h = f2bf(f);
    w1th[n * HID + k] = h;
    w1tl[n * HID + k] = f2bf(f - bf2f(h));
}

__global__ void build_weff_t(const float* __restrict__ eqw,
                             const int* __restrict__ gmap,
                             const int* __restrict__ fpinv,
                             unsigned short* __restrict__ weffh,
                             unsigned short* __restrict__ weffl) {
    int h = threadIdx.x;                 // 128
    int blk = blockIdx.x;                // u*64 + r
    int u = blk >> 6, r = blk & 63;
    float acc = 0.f;
    for (int p = 0; p < GG; ++p) {
        int g = gmap[u * GG + p];
        int q = fpinv[p * QF + r];
        acc += eqw[(g * QF + q) * HID + h];
    }
    acc *= (1.f / GG);
    unsigned short hh = f2bf(acc);
    weffh[(u * HID + h) * QF + r] = hh;
    weffl[(u * HID + h) * QF + r] = f2bf(acc - bf2f(hh));
}

#define XS_STR 72    // ushort stride (144 B, 16B mult, +4 bank skew/row)
#define HB_STR 136   // ushort stride (272 B, 16B mult, +4 bank skew/row)

__global__ __launch_bounds__(256, 3)
void mlp_mfma(const unsigned short* __restrict__ xh,
              const unsigned short* __restrict__ xl,
              const unsigned short* __restrict__ weffh,
              const unsigned short* __restrict__ weffl,
              const unsigned short* __restrict__ w1th,
              const unsigned short* __restrict__ w1tl,
              const float* __restrict__ b1,
              const float* __restrict__ misc,
              float* __restrict__ m) {
    __shared__ __align__(16) unsigned short xsH[64 * XS_STR];
    __shared__ __align__(16) unsigned short xsL[64 * XS_STR];
    __shared__ __align__(16) unsigned short hbH[64 * HB_STR];
    __shared__ __align__(16) unsigned short hbL[64 * HB_STR];

    // XCD-aware decode: each XCD owns 15 u-panels (L2 working set ~1.1 MB)
    int wgid = blockIdx.x;
    int xcd = wgid & 7, j = wgid >> 3;     // j in [0,480)
    int u = xcd * 15 + (j % 15);
    int tile = j / 15;                      // [0,32)
    int rowbase = tile * 64;

    int tid = threadIdx.x;
    int w = tid >> 6, lane = tid & 63;
    int lm = lane & 15, kg = lane >> 4;
    int colbase = w * 32;                   // wave's 32-col slice

    // ---- early independent loads: Weff slice (stage A B-frags) + misc ----
    bf16x8 wef[2][2][2];                    // [nt][ks][hi/lo]
    const unsigned short* whp = weffh + (unsigned)(u * HID) * QF;
    const unsigned short* wlp = weffl + (unsigned)(u * HID) * QF;
#pragma unroll
    for (int nt = 0; nt < 2; ++nt)
#pragma unroll
        for (int ks = 0; ks < 2; ++ks) {
            int off = (colbase + nt * 16 + lm) * QF + ks * 32 + kg * 8;
            wef[nt][ks][0] = *(const bf16x8*)(whp + off);
            wef[nt][ks][1] = *(const bf16x8*)(wlp + off);
        }
    float bm[2]  = {misc[colbase + lm], misc[colbase + 16 + lm]};
    float b1v[2] = {b1[colbase + lm], b1[colbase + 16 + lm]};
    float wmv[2] = {misc[HID + colbase + lm], misc[HID + colbase + 16 + lm]};

    // ---- cooperative X stage: 64x64 hi/lo into LDS ----
    const unsigned short* xhp = xh + rowbase * QF;
    const unsigned short* xlp = xl + rowbase * QF;
#pragma unroll
    for (int i = tid; i < 64 * 8; i += 256) {
        int row = i >> 3, c8 = (i & 7) * 8;
        *(ushort8*)(xsH + row * XS_STR + c8) = *(const ushort8*)(xhp + row * QF + c8);
        *(ushort8*)(xsL + row * XS_STR + c8) = *(const ushort8*)(xlp + row * QF + c8);
    }
    __syncthreads();

    // ---- stage A: E[64 rows][32-col slice] ----
    f32x4 acc[4][2];
#pragma unroll
    for (int mt = 0; mt < 4; ++mt)
#pragma unroll
        for (int nt = 0; nt < 2; ++nt) acc[mt][nt] = (f32x4){0.f, 0.f, 0.f, 0.f};

#pragma unroll
    for (int mt = 0; mt < 4; ++mt) {
#pragma unroll
        for (int ks = 0; ks < 2; ++ks) {
            bf16x8 ah = *(const bf16x8*)(xsH + (mt * 16 + lm) * XS_STR + ks * 32 + kg * 8);
            bf16x8 al = *(const bf16x8*)(xsL + (mt * 16 + lm) * XS_STR + ks * 32 + kg * 8);
#pragma unroll
            for (int nt = 0; nt < 2; ++nt) {
                acc[mt][nt] = __builtin_amdgcn_mfma_f32_16x16x32_bf16(ah, wef[nt][ks][0], acc[mt][nt], 0, 0, 0);
                acc[mt][nt] = __builtin_amdgcn_mfma_f32_16x16x32_bf16(ah, wef[nt][ks][1], acc[mt][nt], 0, 0, 0);
                acc[mt][nt] = __builtin_amdgcn_mfma_f32_16x16x32_bf16(al, wef[nt][ks][0], acc[mt][nt], 0, 0, 0);
            }
        }
    }

    // ---- issue W1 slice loads now (consumed after barrier; hidden under epilogue-A) ----
    bf16x8 w1f[2][4][2];                    // [nt][ks][hi/lo]
#pragma unroll
    for (int nt = 0; nt < 2; ++nt)
#pragma unroll
        for (int ks = 0; ks < 4; ++ks) {
            int off = (colbase + nt * 16 + lm) * HID + ks * 32 + kg * 8;
            w1f[nt][ks][0] = *(const bf16x8*)(w1th + off);
            w1f[nt][ks][1] = *(const bf16x8*)(w1tl + off);
        }

    // ---- relu(e+bmean), split hi/lo -> block-shared hbuf ----
#pragma unroll
    for (int mt = 0; mt < 4; ++mt)
#pragma unroll
        for (int nt = 0; nt < 2; ++nt) {
            int col = colbase + nt * 16 + lm;
#pragma unroll
            for (int r = 0; r < 4; ++r) {
                int row = mt * 16 + kg * 4 + r;
                float e = acc[mt][nt][r] + bm[nt];
                e = e > 0.f ? e : 0.f;
                unsigned short eh = f2bf(e);
                unsigned short el = f2bf(e - bf2f(eh));
                hbH[row * HB_STR + col] = eh;
                hbL[row * HB_STR + col] = el;
            }
        }
    __syncthreads();

    // ---- stage B: H2[64 rows][32-col slice], B-frags in registers ----
    f32x4 acc2[4][2];
#pragma unroll
    for (int mt = 0; mt < 4; ++mt)
#pragma unroll
        for (int nt = 0; nt < 2; ++nt) acc2[mt][nt] = (f32x4){0.f, 0.f, 0.f, 0.f};

#pragma unroll
    for (int mt = 0; mt < 4; ++mt) {
#pragma unroll
        for (int ks = 0; ks < 4; ++ks) {
            bf16x8 ah = *(const bf16x8*)(hbH + (mt * 16 + lm) * HB_STR + ks * 32 + kg * 8);
            bf16x8 al = *(const bf16x8*)(hbL + (mt * 16 + lm) * HB_STR + ks * 32 + kg * 8);
#pragma unroll
            for (int nt = 0; nt < 2; ++nt) {
                acc2[mt][nt] = __builtin_amdgcn_mfma_f32_16x16x32_bf16(ah, w1f[nt][ks][0], acc2[mt][nt], 0, 0, 0);
                acc2[mt][nt] = __builtin_amdgcn_mfma_f32_16x16x32_bf16(ah, w1f[nt][ks][1], acc2[mt][nt], 0, 0, 0);
                acc2[mt][nt] = __builtin_amdgcn_mfma_f32_16x16x32_bf16(al, w1f[nt][ks][0], acc2[mt][nt], 0, 0, 0);
            }
        }
    }

    // ---- epilogue: partial m over this wave's 32 cols, reduce over lm ----
    float ps[4][4];                         // [mt][r]
#pragma unroll
    for (int mt = 0; mt < 4; ++mt)
#pragma unroll
        for (int r = 0; r < 4; ++r) {
            float s = 0.f;
#pragma unroll
            for (int nt = 0; nt < 2; ++nt) {
                float v = acc2[mt][nt][r] + b1v[nt];
                v = v > 0.f ? v : 0.f;
                s += v * wmv[nt];
            }
            ps[mt][r] = s;
        }
#pragma unroll
    for (int off = 1; off < 16; off <<= 1)
#pragma unroll
        for (int mt = 0; mt < 4; ++mt)
#pragma unroll
            for (int r = 0; r < 4; ++r) ps[mt][r] += __shfl_xor(ps[mt][r], off);

    float* msum = (float*)xsH;              // xs dead after stage-A barrier
    if (lm == 0) {
#pragma unroll
        for (int mt = 0; mt < 4; ++mt)
#pragma unroll
            for (int r = 0; r < 4; ++r)
                msum[(mt * 16 + kg * 4 + r) * 4 + w] = ps[mt][r];
    }
    __syncthreads();
    if (tid < 64) {
        float s = msum[tid * 4 + 0] + msum[tid * 4 + 1] +
                  msum[tid * 4 + 2] + msum[tid * 4 + 3];
        m[u * BTOT + rowbase + tid] = s;
    }
}

__global__ void reduce_out(const float* __restrict__ m,
                           const int* __restrict__ ubycoset,
                           const float* __restrict__ misc,
                           float* __restrict__ out) {
    int idx = blockIdx.x * 256 + threadIdx.x;   // bt*20 + a
    if (idx >= BTOT * NACT) return;
    int bt = idx / NACT, a = idx % NACT;
    float s = 0.f;
#pragma unroll
    for (int j = 0; j < 6; ++j) s += m[ubycoset[a * 6 + j] * BTOT + bt];
    out[idx] = s * (1.f / 6.f) + misc[2 * HID];
}

extern "C" void kernel_launch(void* const* d_in, const int* in_sizes, int n_in,
                              void* d_out, int out_size, void* d_ws, size_t ws_size,
                              hipStream_t stream) {
    const float* x       = (const float*)d_in[0];
    const float* eqw     = (const float*)d_in[1];
    const float* eq_bias = (const float*)d_in[2];
    const float* W1      = (const float*)d_in[3];
    const float* b1      = (const float*)d_in[4];
    const float* Wout    = (const float*)d_in[5];
    const float* bout    = (const float*)d_in[6];
    float* out           = (float*)d_out;

    char* ws = (char*)d_ws;
    unsigned short* weffh = (unsigned short*)(ws + WEFFH_OFF);
    unsigned short* weffl = (unsigned short*)(ws + WEFFL_OFF);
    unsigned short* xhb   = (unsigned short*)(ws + XH_OFF);
    unsigned short* xlb   = (unsigned short*)(ws + XL_OFF);
    unsigned short* w1th  = (unsigned short*)(ws + W1TH_OFF);
    unsigned short* w1tl  = (unsigned short*)(ws + W1TL_OFF);
    float* mbuf   = (float*)(ws + M_OFF);
    float* misc   = (float*)(ws + MISC_OFF);
    int* gmap     = (int*)(ws + GMAP_OFF);
    int* fpinv    = (int*)(ws + FPINV_OFF);
    int* ubycoset = (int*)(ws + UBYC_OFF);

    hipLaunchKernelGGL(build_tables, dim3(1), dim3(128), 0, stream,
                       gmap, fpinv, ubycoset);
    hipLaunchKernelGGL(build_misc, dim3(1), dim3(128), 0, stream,
                       eq_bias, Wout, bout, misc);
    hipLaunchKernelGGL(split_x, dim3((BTOT * QF + 255) / 256), dim3(256), 0, stream,
                       x, xhb, xlb);
    hipLaunchKernelGGL(split_w1t, dim3((HID * HID + 255) / 256), dim3(256), 0, stream,
                       W1, w1th, w1tl);
    hipLaunchKernelGGL(build_weff_t, dim3(GG * QF), dim3(HID), 0, stream,
                       eqw, gmap, fpinv, weffh, weffl);
    hipLaunchKernelGGL(mlp_mfma, dim3(3840), dim3(256), 0, stream,
                       xhb, xlb, weffh, weffl, w1th, w1tl, b1, misc, mbuf);
    hipLaunchKernelGGL(reduce_out, dim3((BTOT * NACT + 255) / 256), dim3(256), 0, stream,
                       mbuf, ubycoset, misc, out);
}